// Round 2
// baseline (371.462 us; speedup 1.0000x reference)
//
#include <hip/hip_runtime.h>
#include <math.h>

#define WAVE 64

// Shapes are fixed by the reference: B=64, T=2048, Q=512, K=512.

// ---------------------------------------------------------------------------
// Kernel 1: mids[b,k] = sum_q W[k,q] * query[b,q]
// Each wave computes 8 consecutive k outputs for one b.
// Lane holds query[b] fragment (8 floats) in registers, reused for all 8 W rows.
// waves = 64*512/8 = 4096 -> 1024 waves... 4096/4 = 1024? 4096 waves / 4 per
// block = 1024 blocks? No: 4096 waves, 256-thread blocks (4 waves) -> 1024 blocks.
// ---------------------------------------------------------------------------
__global__ void mids_kernel(const float* __restrict__ W,
                            const float* __restrict__ query,
                            float* __restrict__ mids) {
    const int gwave = (int)((blockIdx.x * blockDim.x + threadIdx.x) >> 6);
    const int lane  = threadIdx.x & 63;
    const int b  = gwave >> 6;          // 64 waves per batch row (512/8)
    const int k0 = (gwave & 63) * 8;

    const float4* qrow = (const float4*)(query + (size_t)b * 512);
    const float4 q0 = qrow[lane];
    const float4 q1 = qrow[lane + 64];

    float s[8];
    #pragma unroll
    for (int r = 0; r < 8; ++r) {
        const float4* wrow = (const float4*)(W + (size_t)(k0 + r) * 512);
        float4 a = wrow[lane];
        float4 c = wrow[lane + 64];
        s[r] = a.x*q0.x + a.y*q0.y + a.z*q0.z + a.w*q0.w
             + c.x*q1.x + c.y*q1.y + c.z*q1.z + c.w*q1.w;
    }
    // 8 independent butterfly reduces, interleaved for latency hiding
    #pragma unroll
    for (int off = 32; off > 0; off >>= 1) {
        #pragma unroll
        for (int r = 0; r < 8; ++r)
            s[r] += __shfl_xor(s[r], off, WAVE);
    }
    if (lane == 0) {
        float4* dst = (float4*)(mids + (size_t)gwave * 8);
        dst[0] = make_float4(s[0], s[1], s[2], s[3]);
        dst[1] = make_float4(s[4], s[5], s[6], s[7]);
    }
}

// ---------------------------------------------------------------------------
// Kernel 2: scores[b,t] = tanhf(sum_k key[b,t,k] * mids[b,k] + bias)
// Each wave handles 16 consecutive t-rows of one batch (chunks never cross b:
// 2048 rows/b is a multiple of 16). mids[b] fragment loaded once per wave.
// Rows processed 4 at a time: 8 float4 key loads in flight, 4 independent
// reduce chains, one coalesced float4 store per group.
// waves = 131072/16 = 8192 -> 2048 blocks of 256.
// ---------------------------------------------------------------------------
__global__ void scores_kernel(const float* __restrict__ key,
                              const float* __restrict__ mids,
                              const float* __restrict__ bias,
                              float* __restrict__ out) {
    const int gwave = (int)((blockIdx.x * blockDim.x + threadIdx.x) >> 6);
    const int lane  = threadIdx.x & 63;
    const int row0  = gwave * 16;          // flattened (b*T + t)
    const int b     = row0 >> 11;          // T = 2048

    const float4* mrow = (const float4*)(mids + (size_t)b * 512);
    const float4 m0 = mrow[lane];
    const float4 m1 = mrow[lane + 64];
    const float bv = bias[0];

    const float4* kbase = (const float4*)key + (size_t)row0 * 128;  // 128 f4/row

    #pragma unroll
    for (int r = 0; r < 16; r += 4) {
        float4 a0 = kbase[(size_t)(r+0)*128 + lane];
        float4 c0 = kbase[(size_t)(r+0)*128 + lane + 64];
        float4 a1 = kbase[(size_t)(r+1)*128 + lane];
        float4 c1 = kbase[(size_t)(r+1)*128 + lane + 64];
        float4 a2 = kbase[(size_t)(r+2)*128 + lane];
        float4 c2 = kbase[(size_t)(r+2)*128 + lane + 64];
        float4 a3 = kbase[(size_t)(r+3)*128 + lane];
        float4 c3 = kbase[(size_t)(r+3)*128 + lane + 64];

        float s0 = a0.x*m0.x + a0.y*m0.y + a0.z*m0.z + a0.w*m0.w
                 + c0.x*m1.x + c0.y*m1.y + c0.z*m1.z + c0.w*m1.w;
        float s1 = a1.x*m0.x + a1.y*m0.y + a1.z*m0.z + a1.w*m0.w
                 + c1.x*m1.x + c1.y*m1.y + c1.z*m1.z + c1.w*m1.w;
        float s2 = a2.x*m0.x + a2.y*m0.y + a2.z*m0.z + a2.w*m0.w
                 + c2.x*m1.x + c2.y*m1.y + c2.z*m1.z + c2.w*m1.w;
        float s3 = a3.x*m0.x + a3.y*m0.y + a3.z*m0.z + a3.w*m0.w
                 + c3.x*m1.x + c3.y*m1.y + c3.z*m1.z + c3.w*m1.w;

        #pragma unroll
        for (int off = 32; off > 0; off >>= 1) {
            s0 += __shfl_xor(s0, off, WAVE);
            s1 += __shfl_xor(s1, off, WAVE);
            s2 += __shfl_xor(s2, off, WAVE);
            s3 += __shfl_xor(s3, off, WAVE);
        }
        if (lane == 0) {
            *(float4*)(out + (size_t)row0 + r) =
                make_float4(tanhf(s0 + bv), tanhf(s1 + bv),
                            tanhf(s2 + bv), tanhf(s3 + bv));
        }
    }
}

// ---------------------------------------------------------------------------
// Kernel 3: in-place softmax over T=2048 per batch row. 64 blocks x 256 thr.
// ---------------------------------------------------------------------------
__global__ void softmax_kernel(float* __restrict__ out, int T) {
    const int b    = blockIdx.x;
    const int tid  = threadIdx.x;
    const int lane = tid & (WAVE - 1);
    const int wid  = tid >> 6;
    float* row = out + (size_t)b * T;

    __shared__ float red[4];

    float vals[8];
    float m = -INFINITY;
    #pragma unroll
    for (int i = 0; i < 8; ++i) {
        vals[i] = row[tid + i * 256];
        m = fmaxf(m, vals[i]);
    }
    #pragma unroll
    for (int off = 32; off > 0; off >>= 1)
        m = fmaxf(m, __shfl_xor(m, off, WAVE));
    if (lane == 0) red[wid] = m;
    __syncthreads();
    m = fmaxf(fmaxf(red[0], red[1]), fmaxf(red[2], red[3]));
    __syncthreads();

    float s = 0.f;
    #pragma unroll
    for (int i = 0; i < 8; ++i) {
        vals[i] = expf(vals[i] - m);
        s += vals[i];
    }
    #pragma unroll
    for (int off = 32; off > 0; off >>= 1)
        s += __shfl_xor(s, off, WAVE);
    if (lane == 0) red[wid] = s;
    __syncthreads();
    s = red[0] + red[1] + red[2] + red[3];

    float inv = 1.f / s;
    #pragma unroll
    for (int i = 0; i < 8; ++i)
        row[tid + i * 256] = vals[i] * inv;
}

// ---------------------------------------------------------------------------
extern "C" void kernel_launch(void* const* d_in, const int* in_sizes, int n_in,
                              void* d_out, int out_size, void* d_ws, size_t ws_size,
                              hipStream_t stream) {
    const float* query = (const float*)d_in[0];   // [B, Q]
    const float* key   = (const float*)d_in[1];   // [B, T, K]
    const float* W     = (const float*)d_in[2];   // [K, Q]
    const float* bias  = (const float*)d_in[3];   // [1]
    float* out  = (float*)d_out;                  // [B, T]
    float* mids = (float*)d_ws;                   // [B, K] scratch (128 KB)

    const int B = 64, T = 2048;

    // 1) mids: 4096 waves (8 k-outputs each) -> 1024 blocks
    mids_kernel<<<1024, 256, 0, stream>>>(W, query, mids);

    // 2) scores: 8192 waves (16 rows each) -> 2048 blocks
    scores_kernel<<<2048, 256, 0, stream>>>(key, mids, bias, out);

    // 3) softmax: one block per batch row
    softmax_kernel<<<B, 256, 0, stream>>>(out, T);
}

// Round 4
// 345.338 us; speedup vs baseline: 1.0756x; 1.0756x over previous
//
#include <hip/hip_runtime.h>
#include <math.h>

#define WAVE 64

// Native clang vector type — required for __builtin_nontemporal_load
// (HIP_vector_type<float,4> is a struct and is rejected).
typedef float nfloat4 __attribute__((ext_vector_type(4)));

// Shapes fixed by reference: B=64, T=2048, Q=512, K=512.

// ---------------------------------------------------------------------------
// Kernel 1: mids[b,k] = sum_q W[k,q] * query[b,q]
// One wave per 8 consecutive k for one b. query[b] fragment held in regs.
// W (1 MB) is L2-resident across its 64 batch re-reads.
// ---------------------------------------------------------------------------
__global__ void mids_kernel(const float* __restrict__ W,
                            const float* __restrict__ query,
                            float* __restrict__ mids) {
    const int gwave = (int)((blockIdx.x * blockDim.x + threadIdx.x) >> 6);
    const int lane  = threadIdx.x & 63;
    const int b  = gwave >> 6;          // 64 waves per batch row (512/8)
    const int k0 = (gwave & 63) * 8;

    const float4* qrow = (const float4*)(query + (size_t)b * 512);
    const float4 q0 = qrow[lane];
    const float4 q1 = qrow[lane + 64];

    float s[8];
    #pragma unroll
    for (int r = 0; r < 8; ++r) {
        const float4* wrow = (const float4*)(W + (size_t)(k0 + r) * 512);
        float4 a = wrow[lane];
        float4 c = wrow[lane + 64];
        s[r] = a.x*q0.x + a.y*q0.y + a.z*q0.z + a.w*q0.w
             + c.x*q1.x + c.y*q1.y + c.z*q1.z + c.w*q1.w;
    }
    #pragma unroll
    for (int off = 32; off > 0; off >>= 1) {
        #pragma unroll
        for (int r = 0; r < 8; ++r)
            s[r] += __shfl_xor(s[r], off, WAVE);
    }
    if (lane == 0) {
        float4* dst = (float4*)(mids + (size_t)gwave * 8);
        dst[0] = make_float4(s[0], s[1], s[2], s[3]);
        dst[1] = make_float4(s[4], s[5], s[6], s[7]);
    }
}

// ---------------------------------------------------------------------------
// Kernel 2: scores[b,t] = tanhf(key[b,t,:] . mids[b,:] + bias)
// 16 rows per wave, two 8-row groups: 16 nontemporal float4 loads in flight
// before any reduction. key is streamed once -> nt hint keeps L2 free for
// mids/W. Butterfly reduce, two float4 stores per group.
// 8192 waves -> 2048 blocks of 256.
// ---------------------------------------------------------------------------
__global__ void scores_kernel(const float* __restrict__ key,
                              const float* __restrict__ mids,
                              const float* __restrict__ bias,
                              float* __restrict__ out) {
    const int gwave = (int)((blockIdx.x * blockDim.x + threadIdx.x) >> 6);
    const int lane  = threadIdx.x & 63;
    const int row0  = gwave * 16;          // flattened (b*T + t)
    const int b     = row0 >> 11;          // T = 2048

    const float4* mrow = (const float4*)(mids + (size_t)b * 512);
    const float4 m0 = mrow[lane];
    const float4 m1 = mrow[lane + 64];
    const float bv = bias[0];

    const nfloat4* kbase = (const nfloat4*)key + (size_t)row0 * 128;  // 128 f4/row

    #pragma unroll
    for (int g = 0; g < 2; ++g) {          // two 8-row groups
        const int r0 = g * 8;
        nfloat4 a[8], c[8];
        #pragma unroll
        for (int r = 0; r < 8; ++r) {
            a[r] = __builtin_nontemporal_load(&kbase[(size_t)(r0 + r) * 128 + lane]);
            c[r] = __builtin_nontemporal_load(&kbase[(size_t)(r0 + r) * 128 + lane + 64]);
        }
        float s[8];
        #pragma unroll
        for (int r = 0; r < 8; ++r) {
            s[r] = a[r].x*m0.x + a[r].y*m0.y + a[r].z*m0.z + a[r].w*m0.w
                 + c[r].x*m1.x + c[r].y*m1.y + c[r].z*m1.z + c[r].w*m1.w;
        }
        #pragma unroll
        for (int off = 32; off > 0; off >>= 1) {
            #pragma unroll
            for (int r = 0; r < 8; ++r)
                s[r] += __shfl_xor(s[r], off, WAVE);
        }
        if (lane == 0) {
            *(float4*)(out + (size_t)row0 + r0) =
                make_float4(tanhf(s[0] + bv), tanhf(s[1] + bv),
                            tanhf(s[2] + bv), tanhf(s[3] + bv));
            *(float4*)(out + (size_t)row0 + r0 + 4) =
                make_float4(tanhf(s[4] + bv), tanhf(s[5] + bv),
                            tanhf(s[6] + bv), tanhf(s[7] + bv));
        }
    }
}

// ---------------------------------------------------------------------------
// Kernel 3: in-place softmax over T=2048 per batch row. 64 blocks x 256 thr.
// ---------------------------------------------------------------------------
__global__ void softmax_kernel(float* __restrict__ out, int T) {
    const int b    = blockIdx.x;
    const int tid  = threadIdx.x;
    const int lane = tid & (WAVE - 1);
    const int wid  = tid >> 6;
    float* row = out + (size_t)b * T;

    __shared__ float red[4];

    float vals[8];
    float m = -INFINITY;
    #pragma unroll
    for (int i = 0; i < 8; ++i) {
        vals[i] = row[tid + i * 256];
        m = fmaxf(m, vals[i]);
    }
    #pragma unroll
    for (int off = 32; off > 0; off >>= 1)
        m = fmaxf(m, __shfl_xor(m, off, WAVE));
    if (lane == 0) red[wid] = m;
    __syncthreads();
    m = fmaxf(fmaxf(red[0], red[1]), fmaxf(red[2], red[3]));
    __syncthreads();

    float s = 0.f;
    #pragma unroll
    for (int i = 0; i < 8; ++i) {
        vals[i] = expf(vals[i] - m);
        s += vals[i];
    }
    #pragma unroll
    for (int off = 32; off > 0; off >>= 1)
        s += __shfl_xor(s, off, WAVE);
    if (lane == 0) red[wid] = s;
    __syncthreads();
    s = red[0] + red[1] + red[2] + red[3];

    float inv = 1.f / s;
    #pragma unroll
    for (int i = 0; i < 8; ++i)
        row[tid + i * 256] = vals[i] * inv;
}

// ---------------------------------------------------------------------------
extern "C" void kernel_launch(void* const* d_in, const int* in_sizes, int n_in,
                              void* d_out, int out_size, void* d_ws, size_t ws_size,
                              hipStream_t stream) {
    const float* query = (const float*)d_in[0];   // [B, Q]
    const float* key   = (const float*)d_in[1];   // [B, T, K]
    const float* W     = (const float*)d_in[2];   // [K, Q]
    const float* bias  = (const float*)d_in[3];   // [1]
    float* out  = (float*)d_out;                  // [B, T]
    float* mids = (float*)d_ws;                   // [B, K] scratch (128 KB)

    const int B = 64, T = 2048;

    // 1) mids: 4096 waves (8 k-outputs each) -> 1024 blocks
    mids_kernel<<<1024, 256, 0, stream>>>(W, query, mids);

    // 2) scores: 8192 waves (16 rows each) -> 2048 blocks
    scores_kernel<<<2048, 256, 0, stream>>>(key, mids, bias, out);

    // 3) softmax: one block per batch row
    softmax_kernel<<<B, 256, 0, stream>>>(out, T);
}